// Round 8
// baseline (1411.979 us; speedup 1.0000x reference)
//
#include <hip/hip_runtime.h>
#include <hip/hip_bf16.h>
#include <math.h>

#define B_ 32
#define T_ 128
#define V_ 32000
#define D_ 512
#define H_ 512

typedef __attribute__((ext_vector_type(8))) short bf16x8;
typedef __attribute__((ext_vector_type(4))) float f32x4;
typedef __attribute__((ext_vector_type(2))) unsigned long long u64x2;

#define AS1 __attribute__((address_space(1)))
#define AS3 __attribute__((address_space(3)))

__device__ __forceinline__ unsigned short f2bf(float x) {
  unsigned int b = __float_as_uint(x);
  return (unsigned short)((b + 0x7FFFu + ((b >> 16) & 1u)) >> 16);
}
__device__ __forceinline__ float bf2f(unsigned short u) {
  return __uint_as_float(((unsigned int)u) << 16);
}
__device__ __forceinline__ float sigm(float x) { return 1.0f / (1.0f + __expf(-x)); }
__device__ __forceinline__ float tanh_fast(float x) { return 1.0f - 2.0f / (__expf(2.0f * x) + 1.0f); }

// ---------------- embedding gather -> bf16
__global__ __launch_bounds__(64) void embed_bf_kernel(const int* __restrict__ dst,
                                                      const float* __restrict__ E,
                                                      unsigned short* __restrict__ embbf) {
  int rt = blockIdx.x;           // t*32 + b
  int t = rt >> 5, b = rt & 31;
  int v = dst[b * T_ + t];
  const float4* src = (const float4*)(E + (size_t)v * D_);
  ushort4* d = (ushort4*)(embbf + (size_t)rt * D_);
  #pragma unroll
  for (int r = 0; r < 2; ++r) {
    float4 x = src[threadIdx.x + r * 64];
    ushort4 o; o.x = f2bf(x.x); o.y = f2bf(x.y); o.z = f2bf(x.z); o.w = f2bf(x.w);
    d[threadIdx.x + r * 64] = o;
  }
}

// ---------------- generic f32 -> bf16
__global__ void cvt_kernel(const float* __restrict__ in, unsigned short* __restrict__ out, int n4) {
  int stride = gridDim.x * blockDim.x;
  for (int i = blockIdx.x * blockDim.x + threadIdx.x; i < n4; i += stride) {
    float4 v = ((const float4*)in)[i];
    ushort4 o; o.x = f2bf(v.x); o.y = f2bf(v.y); o.z = f2bf(v.z); o.w = f2bf(v.w);
    ((ushort4*)out)[i] = o;
  }
}

// ---------------- W1bf[r][c] = bf16(Wih[r][c]), c<512 (row stride 1024)
__global__ void cvt_w1_kernel(const float* __restrict__ Wih, unsigned short* __restrict__ W1bf, int n4) {
  int stride = gridDim.x * blockDim.x;
  for (int i = blockIdx.x * blockDim.x + threadIdx.x; i < n4; i += stride) {
    int flat = i * 4;
    int r = flat >> 9, c = flat & 511;
    float4 v = *(const float4*)(Wih + (size_t)r * 1024 + c);
    ushort4 o; o.x = f2bf(v.x); o.y = f2bf(v.y); o.z = f2bf(v.z); o.w = f2bf(v.w);
    ((ushort4*)W1bf)[i] = o;
  }
}

// ---------------- Wrs[grow][chunk^(grow&7)] = bf16(Wih[grow][512+k] + Whh[grow][k])
__global__ void wr_prep_swz_kernel(const float* __restrict__ Wih, const float* __restrict__ Whh,
                                   unsigned short* __restrict__ Wrs, int n4) {
  int stride = gridDim.x * blockDim.x;
  for (int i = blockIdx.x * blockDim.x + threadIdx.x; i < n4; i += stride) {
    int flat = i * 4;
    int grow = flat >> 9, k = flat & 511;
    float4 a = *(const float4*)(Wih + (size_t)grow * 1024 + 512 + k);
    float4 b = ((const float4*)Whh)[i];
    ushort4 o;
    o.x = f2bf(a.x + b.x); o.y = f2bf(a.y + b.y); o.z = f2bf(a.z + b.z); o.w = f2bf(a.w + b.w);
    int chunk = (k >> 3) ^ (grow & 7);
    *(ushort4*)(Wrs + (size_t)grow * 512 + chunk * 8 + (k & 7)) = o;
  }
}

// ---------------- pre-GEMM: preA2[t][grow][b] = bf16(emb . W1 + bias)
__global__ __launch_bounds__(256) void gemm_pre_kernel(
    const unsigned short* __restrict__ A,
    const unsigned short* __restrict__ Bm,
    const float* __restrict__ bih, const float* __restrict__ bhh,
    unsigned short* __restrict__ preA2)
{
  __shared__ unsigned short ldsA[2][128 * 32];
  __shared__ unsigned short ldsB[2][128 * 32];
  const int tid = threadIdx.x;
  const int lane = tid & 63;
  const int wid = tid >> 6;
  const int wm = wid >> 1, wn = wid & 1;
  const int m0 = blockIdx.y * 128;
  const int n0 = blockIdx.x * 128;
  const int srow = lane >> 2;
  const int scol = (lane & 3) * 8;

  f32x4 acc[4][4] = {};
  const int NK = 512 / 32;

  auto stage = [&](int kk, int buf) {
    const int k0 = kk * 32;
    #pragma unroll
    for (int c = 0; c < 2; ++c) {
      const int r = wid * 32 + c * 16;
      const unsigned short* sa = A  + (size_t)(m0 + r + srow) * 512 + k0 + scol;
      const unsigned short* sb = Bm + (size_t)(n0 + r + srow) * 512 + k0 + scol;
      __builtin_amdgcn_global_load_lds((const AS1 void*)sa, (AS3 void*)&ldsA[buf][r * 32], 16, 0, 0);
      __builtin_amdgcn_global_load_lds((const AS1 void*)sb, (AS3 void*)&ldsB[buf][r * 32], 16, 0, 0);
    }
  };

  stage(0, 0);
  __syncthreads();

  const int rl = lane & 15;
  const int kb = lane >> 4;

  for (int kk = 0; kk < NK; ++kk) {
    const int buf = kk & 1;
    if (kk + 1 < NK) stage(kk + 1, buf ^ 1);
    const bf16x8* Af = (const bf16x8*)&ldsA[buf][0];
    const bf16x8* Bf = (const bf16x8*)&ldsB[buf][0];
    bf16x8 av[4], bv[4];
    #pragma unroll
    for (int mi = 0; mi < 4; ++mi) av[mi] = Af[(wm * 64 + mi * 16 + rl) * 4 + kb];
    #pragma unroll
    for (int ni = 0; ni < 4; ++ni) bv[ni] = Bf[(wn * 64 + ni * 16 + rl) * 4 + kb];
    #pragma unroll
    for (int mi = 0; mi < 4; ++mi)
      #pragma unroll
      for (int ni = 0; ni < 4; ++ni)
        acc[mi][ni] = __builtin_amdgcn_mfma_f32_16x16x32_bf16(av[mi], bv[ni], acc[mi][ni], 0, 0, 0);
    __syncthreads();
  }

  const int rb = (lane >> 4) * 4;
  #pragma unroll
  for (int mi = 0; mi < 4; ++mi)
    #pragma unroll
    for (int ni = 0; ni < 4; ++ni) {
      int mbase = m0 + wm * 64 + mi * 16 + rb;
      int col   = n0 + wn * 64 + ni * 16 + rl;
      float bb = bih[col] + bhh[col];
      ushort4 o;
      o.x = f2bf(acc[mi][ni][0] + bb); o.y = f2bf(acc[mi][ni][1] + bb);
      o.z = f2bf(acc[mi][ni][2] + bb); o.w = f2bf(acc[mi][ni][3] + bb);
      *(ushort4*)&preA2[((size_t)(mbase >> 5) * 2048 + col) * 32 + (mbase & 31)] = o;
    }
}

// ---------------- preA2[t=0][r][:] += (out0 - h0) @ W2^T
__global__ __launch_bounds__(256) void delta0_kernel(const float* __restrict__ Wih,
                                                     const float* __restrict__ out0,
                                                     const float* __restrict__ h0,
                                                     unsigned short* __restrict__ preA2) {
  const int r = blockIdx.x;
  const int tid = threadIdx.x;
  const int b = tid >> 3, seg = tid & 7;
  __shared__ float red[32][9];
  const float4* o4 = (const float4*)(out0 + (size_t)b * 512 + seg * 64);
  const float4* h4 = (const float4*)(h0 + (size_t)b * 512 + seg * 64);
  const float4* w4 = (const float4*)(Wih + (size_t)r * 1024 + 512 + seg * 64);
  float s = 0.f;
  #pragma unroll
  for (int j = 0; j < 16; ++j) {
    float4 o = o4[j], h = h4[j], w = w4[j];
    s += (o.x - h.x) * w.x + (o.y - h.y) * w.y + (o.z - h.z) * w.z + (o.w - h.w) * w.w;
  }
  red[b][seg] = s;
  __syncthreads();
  if (tid < 32) {
    float t = 0.f;
    #pragma unroll
    for (int j = 0; j < 8; ++j) t += red[tid][j];
    unsigned short* p = preA2 + (size_t)r * 32 + tid;
    *p = f2bf(bf2f(*p) + t);
  }
}

// ---------------- persistent LSTM, 16 blocks x 1024 threads
// Block bid owns k-slots bid*32..bid*32+31 (128 gate rows, 128 KB LDS W, resident).
// Per step: h (32 KB) staged cooperatively into LDS (4 agent atomic u64 loads/thread).
// Sync: per-block flag lines (agent store after barrier-drain), parallel poll.
__global__ __launch_bounds__(1024) void lstm_persist16_kernel(
    const unsigned short* __restrict__ Wrs,   // [2048][512] bf16, chunk-swizzled rows
    const unsigned short* __restrict__ preA2, // [T][2048][32] bf16 (bias folded)
    const float* __restrict__ c0,             // [32][512] f32
    unsigned short* __restrict__ hA,          // [32][512] bf16 ping (h0 at entry)
    unsigned short* __restrict__ hB,          // pong
    unsigned short* __restrict__ Abf,         // [B*T][512] bf16
    unsigned int* __restrict__ flags)         // 16 x 64B lines, zeroed each call
{
  __shared__ unsigned short wlds[128 * 512];            // 128 KB
  __shared__ __align__(16) char hexch[32 * 1024];       // 32 KB: h tile, aliased by gl
  float (*gl)[33] = (float (*)[33])hexch;               // 128 x 33 f32 = 16.9 KB
  const int tid = threadIdx.x, bid = blockIdx.x;
  const int lane = tid & 63, wid = tid >> 6;

  // stage 128 W rows once (pre-swizzled source, linear LDS dest)
  #pragma unroll
  for (int it = 0; it < 8; ++it) {
    int r = it * 16 + wid;
    int grow = (r >> 5) * 512 + bid * 32 + (r & 31);
    const unsigned short* src = Wrs + (size_t)grow * 512 + lane * 8;
    __builtin_amdgcn_global_load_lds((const AS1 void*)src, (AS3 void*)&wlds[r * 512], 16, 0, 0);
  }

  // epilogue ownership: thread -> (batch eb, k-slot ek)
  const int eb = tid >> 5, ek = tid & 31;
  const int ekg = bid * 32 + ek;
  float c_reg = c0[(size_t)eb * 512 + ekg];

  // MFMA roles: wave -> (row-tile rt 0..7, batch-tile bt 0..1)
  const int rt = wid >> 1, bt = wid & 1;
  const int rl = lane & 15, q = lane >> 4;
  const int row = rt * 16 + rl;
  const char* wbase = (const char*)wlds + row * 1024;
  const int rx = (row & 7) << 4;
  const int hrowl = bt * 16 + rl;
  const char* hbase = hexch + hrowl * 1024;
  const int hx = (hrowl & 7) << 4;

  // h staging role: thread -> 32 B (16 elems) of the 32 KB h tile
  const int shr = tid >> 5;                 // h row 0..31
  const int scb = (tid & 31) * 32;          // byte offset in row
  const int srx = (shr & 7) << 4;
  char* sbase = hexch + shr * 1024;

  __syncthreads();

  for (int t = 0; t < T_; ++t) {
    // prefetch preA2 (h-independent) before the spin
    const size_t pbase = (size_t)t * (2048 * 32);
    unsigned short p0 = preA2[pbase + (size_t)(0 * 512 + ekg) * 32 + eb];
    unsigned short p1 = preA2[pbase + (size_t)(1 * 512 + ekg) * 32 + eb];
    unsigned short p2 = preA2[pbase + (size_t)(2 * 512 + ekg) * 32 + eb];
    unsigned short p3 = preA2[pbase + (size_t)(3 * 512 + ekg) * 32 + eb];

    if (t > 0) {
      // parallel poll: 16 threads each watch one producer's flag line
      if (tid < 16) {
        const unsigned want = (unsigned)t;
        unsigned spins = 0;
        while (__hip_atomic_load(&flags[tid * 16], __ATOMIC_RELAXED,
                                 __HIP_MEMORY_SCOPE_AGENT) < want) {
          if (++spins > 50000000u) break;   // bailout: fail validation, don't hang
        }
      }
      __syncthreads();
    }

    const unsigned short* hin = (t & 1) ? hB : hA;
    unsigned short* hout = (t & 1) ? hA : hB;

    // ---- cooperative h stage: 4 atomic u64 loads -> 2 ds_write_b128
    {
      const unsigned long long* hs = (const unsigned long long*)hin + (size_t)tid * 4;
      unsigned long long d0 = __hip_atomic_load(hs + 0, __ATOMIC_RELAXED, __HIP_MEMORY_SCOPE_AGENT);
      unsigned long long d1 = __hip_atomic_load(hs + 1, __ATOMIC_RELAXED, __HIP_MEMORY_SCOPE_AGENT);
      unsigned long long d2 = __hip_atomic_load(hs + 2, __ATOMIC_RELAXED, __HIP_MEMORY_SCOPE_AGENT);
      unsigned long long d3 = __hip_atomic_load(hs + 3, __ATOMIC_RELAXED, __HIP_MEMORY_SCOPE_AGENT);
      u64x2 w0; w0[0] = d0; w0[1] = d1;
      u64x2 w1; w1[0] = d2; w1[1] = d3;
      *(u64x2*)(sbase + ((scb + 0) ^ srx)) = w0;
      *(u64x2*)(sbase + ((scb + 16) ^ srx)) = w1;
    }
    __syncthreads();

    f32x4 acc = {}, acc2 = {};
    #pragma unroll
    for (int kk = 0; kk < 16; kk += 2) {
      int k0 = kk * 32 + q * 8;
      int k1 = k0 + 32;
      bf16x8 av0 = *(const bf16x8*)(wbase + ((k0 * 2) ^ rx));
      bf16x8 bv0 = *(const bf16x8*)(hbase + ((k0 * 2) ^ hx));
      bf16x8 av1 = *(const bf16x8*)(wbase + ((k1 * 2) ^ rx));
      bf16x8 bv1 = *(const bf16x8*)(hbase + ((k1 * 2) ^ hx));
      acc  = __builtin_amdgcn_mfma_f32_16x16x32_bf16(av0, bv0, acc, 0, 0, 0);
      acc2 = __builtin_amdgcn_mfma_f32_16x16x32_bf16(av1, bv1, acc2, 0, 0, 0);
    }
    __syncthreads();    // h-tile reads complete before gl (alias) is written

    #pragma unroll
    for (int j = 0; j < 4; ++j)
      gl[rt * 16 + q * 4 + j][bt * 16 + rl] = acc[j] + acc2[j];
    __syncthreads();

    {
      float g0 = gl[0 * 32 + ek][eb] + bf2f(p0);
      float g1 = gl[1 * 32 + ek][eb] + bf2f(p1);
      float g2 = gl[2 * 32 + ek][eb] + bf2f(p2);
      float g3 = gl[3 * 32 + ek][eb] + bf2f(p3);
      float iv = sigm(g0), fv = sigm(g1), gv = tanh_fast(g2), ov = sigm(g3);
      float cn = fv * c_reg + iv * gv;
      c_reg = cn;
      float hn = ov * tanh_fast(cn);
      unsigned short hb = f2bf(hn);
      int nb = __shfl_down((int)hb, 1);
      if ((ek & 1) == 0) {
        unsigned int pair = (unsigned int)hb | ((unsigned int)nb << 16);
        __hip_atomic_store((unsigned int*)(hout + (size_t)eb * 512 + ekg), pair,
                           __ATOMIC_RELAXED, __HIP_MEMORY_SCOPE_AGENT);
        *(unsigned int*)(Abf + ((size_t)eb * T_ + t) * 512 + ekg) = pair;
      }
    }
    __syncthreads();   // h-stores drained (vmcnt 0 at barrier) before flag

    if (t != T_ - 1 && tid == 0)
      __hip_atomic_store(&flags[bid * 16], (unsigned)(t + 1),
                         __ATOMIC_RELAXED, __HIP_MEMORY_SCOPE_AGENT);
  }
}

// ---------------- projection GEMM (swizzled LDS, cached C stores) + softmax partials
// grid (32 m-tiles [x, fast], 250 n-tiles [y]) -> consecutive blocks share B panel.
__global__ __launch_bounds__(256) void gemm_kernel(
    const unsigned short* __restrict__ A,
    const unsigned short* __restrict__ Bm,
    float* __restrict__ C,
    float* __restrict__ pmax, float* __restrict__ psum)
{
  __shared__ unsigned short ldsA[2][128 * 32];
  __shared__ unsigned short ldsB[2][128 * 32];
  __shared__ float smax[2][128];
  __shared__ float ssum[2][128];
  const int tid = threadIdx.x;
  const int lane = tid & 63;
  const int wid = tid >> 6;
  const int wm = wid >> 1, wn = wid & 1;
  const int m0 = blockIdx.x * 128;
  const int n0 = blockIdx.y * 128;
  const int srow = lane >> 2;

  f32x4 acc[4][4] = {};
  const int NK = 512 / 32;

  // swizzle: LDS chunk c of row r holds global chunk c ^ ((r>>1)&3)
  auto stage = [&](int kk, int buf) {
    const int k0 = kk * 32;
    const int sw = (srow >> 1) & 3;
    const int gc = ((lane & 3) ^ sw) * 8;
    #pragma unroll
    for (int c = 0; c < 2; ++c) {
      const int r = wid * 32 + c * 16;
      const unsigned short* sa = A  + (size_t)(m0 + r + srow) * 512 + k0 + gc;
      const unsigned short* sb = Bm + (size_t)(n0 + r + srow) * 512 + k0 + gc;
      __builtin_amdgcn_global_load_lds((const AS1 void*)sa, (AS3 void*)&ldsA[buf][r * 32], 16, 0, 0);
      __builtin_amdgcn_global_load_lds((const AS1 void*)sb, (AS3 void*)&ldsB[buf][r * 32], 16, 0, 0);
    }
  };

  stage(0, 0);
  __syncthreads();

  const int rl = lane & 15;
  const int kb = lane >> 4;
  const int rsw = kb ^ ((rl >> 1) & 3);

  for (int kk = 0; kk < NK; ++kk) {
    const int buf = kk & 1;
    if (kk + 1 < NK) stage(kk + 1, buf ^ 1);
    const bf16x8* Af = (const bf16x8*)&ldsA[buf][0];
    const bf16x8* Bf = (const bf16x8*)&ldsB[buf][0];
    bf16x8 av[4], bv[4];
    #pragma unroll
    for (int mi = 0; mi < 4; ++mi) av[mi] = Af[(wm * 64 + mi * 16 + rl) * 4 + rsw];
    #pragma unroll
    for (int ni = 0; ni < 4; ++ni) bv[ni] = Bf[(wn * 64 + ni * 16 + rl) * 4 + rsw];
    #pragma unroll
    for (int mi = 0; mi < 4; ++mi)
      #pragma unroll
      for (int ni = 0; ni < 4; ++ni)
        acc[mi][ni] = __builtin_amdgcn_mfma_f32_16x16x32_bf16(av[mi], bv[ni], acc[mi][ni], 0, 0, 0);
    __syncthreads();
  }

  const int rb = kb * 4;
  #pragma unroll
  for (int mi = 0; mi < 4; ++mi)
    #pragma unroll
    for (int ni = 0; ni < 4; ++ni) {
      size_t rrow = (size_t)(m0 + wm * 64 + mi * 16 + rb);
      size_t col = (size_t)(n0 + wn * 64 + ni * 16 + rl);
      #pragma unroll
      for (int j = 0; j < 4; ++j)
        C[(rrow + j) * (size_t)V_ + col] = acc[mi][ni][j];
    }

  // ---- per-tile row max / sum-exp partials ----
  float tm[4][4];
  #pragma unroll
  for (int mi = 0; mi < 4; ++mi)
    #pragma unroll
    for (int j = 0; j < 4; ++j) {
      float m = fmaxf(fmaxf(acc[mi][0][j], acc[mi][1][j]), fmaxf(acc[mi][2][j], acc[mi][3][j]));
      m = fmaxf(m, __shfl_xor(m, 1)); m = fmaxf(m, __shfl_xor(m, 2));
      m = fmaxf(m, __shfl_xor(m, 4)); m = fmaxf(m, __shfl_xor(m, 8));
      tm[mi][j] = m;
    }
  if (rl == 0) {
    #pragma unroll
    for (int mi = 0; mi < 4; ++mi)
      #pragma unroll
      for (int j = 0; j < 4; ++j)
        smax[wn][wm * 64 + mi * 16 + kb * 4 + j] = tm[mi][j];
  }
  __syncthreads();
  float ts[4][4];
  #pragma unroll
  for (int mi = 0; mi < 4; ++mi)
    #pragma unroll
    for (int j = 0; j < 4; ++j) {
      int rlocal = wm * 64 + mi * 16 + kb * 4 + j;
      float M = fmaxf(smax[0][rlocal], smax[1][rlocal]);
      float s = __expf(acc[mi][0][j] - M) + __expf(acc[mi][1][j] - M) +
                __expf(acc[mi][2][j] - M) + __expf(acc[mi][3][j] - M);
      s += __shfl_xor(s, 1); s += __shfl_xor(s, 2);
      s += __shfl_xor(s, 4); s += __shfl_xor(s, 8);
      ts[mi][j] = s;
    }
  if (rl == 0) {
    #pragma unroll
    for (int mi = 0; mi < 4; ++mi)
      #pragma unroll
      for (int j = 0; j < 4; ++j)
        ssum[wn][wm * 64 + mi * 16 + kb * 4 + j] = ts[mi][j];
  }
  __syncthreads();
  if (tid < 128) {
    float M = fmaxf(smax[0][tid], smax[1][tid]);
    float S = ssum[0][tid] + ssum[1][tid];
    pmax[(size_t)(m0 + tid) * 256 + blockIdx.y] = M;
    psum[(size_t)(m0 + tid) * 256 + blockIdx.y] = S;
  }
}

// ---------------- finish: lse from partials, then C[row] -= lse
// plain loads (catch LLC-resident tail of C), nontemporal final stores.
__global__ __launch_bounds__(256) void softmax_finish_kernel(
    float* __restrict__ C, const float* __restrict__ pmax, const float* __restrict__ psum) {
  const size_t row = blockIdx.x;
  const int tid = threadIdx.x, lane = tid & 63, wid = tid >> 6;
  __shared__ float red[4];

  float pm = (tid < 250) ? pmax[row * 256 + tid] : -INFINITY;
  float ps = (tid < 250) ? psum[row * 256 + tid] : 0.f;

  float m = pm;
  #pragma unroll
  for (int off = 32; off > 0; off >>= 1) m = fmaxf(m, __shfl_xor(m, off));
  if (lane == 0) red[wid] = m;
  __syncthreads();
  m = fmaxf(fmaxf(red[0], red[1]), fmaxf(red[2], red[3]));
  __syncthreads();

  float s = (tid < 250) ? ps * __expf(pm - m) : 0.f;
  #pragma unroll
  for (int off = 32; off > 0; off >>= 1) s += __shfl_xor(s, off);
  if (lane == 0) red[wid] = s;
  __syncthreads();
  s = red[0] + red[1] + red[2] + red[3];
  const float lse = m + logf(s);

  f32x4* p4 = (f32x4*)(C + row * (size_t)V_);
  for (int i = tid; i < 8000; i += 256) {
    f32x4 v = p4[i];
    v -= lse;
    __builtin_nontemporal_store(v, &p4[i]);
  }
}

extern "C" void kernel_launch(void* const* d_in, const int* in_sizes, int n_in,
                              void* d_out, int out_size, void* d_ws, size_t ws_size,
                              hipStream_t stream) {
  const int*   dst  = (const int*)d_in[0];
  const float* E    = (const float*)d_in[1];
  const float* Wih  = (const float*)d_in[2];
  const float* Whh  = (const float*)d_in[3];
  const float* bih  = (const float*)d_in[4];
  const float* bhh  = (const float*)d_in[5];
  const float* h0   = (const float*)d_in[6];
  const float* c0   = (const float*)d_in[7];
  const float* out0 = (const float*)d_in[8];
  float* C = (float*)d_out;

  char* ws = (char*)d_ws;
  unsigned short* Ebf   = (unsigned short*)(ws);                      // 32.77 MB
  unsigned short* preA2 = (unsigned short*)(ws + (size_t)33554432);   // 16.78 MB
  unsigned short* Wrs   = (unsigned short*)(ws + (size_t)50331648);   // 2.10 MB
  unsigned short* embbf = (unsigned short*)(ws + (size_t)52428800);   // pre-phase
  float*          pmax  = (float*)(ws + (size_t)52428800);            // post-phase 4.19 MB
  unsigned short* W1bf  = (unsigned short*)(ws + (size_t)56623104);   // pre-phase
  float*          psum  = (float*)(ws + (size_t)56623104);            // post-phase 4.19 MB
  unsigned short* Abf   = (unsigned short*)(ws + (size_t)60817408);   // 4.19 MB
  unsigned short* hb0   = (unsigned short*)(ws + (size_t)65011712);   // 32 KB
  unsigned short* hb1   = (unsigned short*)(ws + (size_t)65044480);   // 32 KB
  unsigned int*   flg   = (unsigned int*)(ws + (size_t)65077248);     // 1 KB (16 x 64B)

  (void)hipMemsetAsync(flg, 0, 1024, stream);

  // --- precompute ---
  embed_bf_kernel<<<dim3(T_ * B_), dim3(64), 0, stream>>>(dst, E, embbf);
  cvt_kernel<<<dim3(2048), dim3(256), 0, stream>>>(E, Ebf, V_ * D_ / 4);
  cvt_w1_kernel<<<dim3(256), dim3(256), 0, stream>>>(Wih, W1bf, 2048 * 512 / 4);
  wr_prep_swz_kernel<<<dim3(256), dim3(256), 0, stream>>>(Wih, Whh, Wrs, 2048 * 512 / 4);

  gemm_pre_kernel<<<dim3(2048 / 128, 4096 / 128), dim3(256), 0, stream>>>(embbf, W1bf, bih, bhh, preA2);
  delta0_kernel<<<dim3(2048), dim3(256), 0, stream>>>(Wih, out0, h0, preA2);
  cvt_kernel<<<dim3(16), dim3(256), 0, stream>>>(h0, hb0, B_ * H_ / 4);

  // --- full recurrence, one launch, 16 blocks ---
  lstm_persist16_kernel<<<dim3(16), dim3(1024), 0, stream>>>(Wrs, preA2, c0, hb0, hb1, Abf, flg);

  // --- projection + fused softmax partials ---
  gemm_kernel<<<dim3(32, 250), dim3(256), 0, stream>>>(Abf, Ebf, C, pmax, psum);
  softmax_finish_kernel<<<dim3(B_ * T_), dim3(256), 0, stream>>>(C, pmax, psum);
}

// Round 9
// 1213.737 us; speedup vs baseline: 1.1633x; 1.1633x over previous
//
#include <hip/hip_runtime.h>
#include <hip/hip_bf16.h>
#include <math.h>

#define B_ 32
#define T_ 128
#define V_ 32000
#define D_ 512
#define H_ 512

typedef __attribute__((ext_vector_type(8))) short bf16x8;
typedef __attribute__((ext_vector_type(4))) float f32x4;
typedef __attribute__((ext_vector_type(2))) unsigned long long u64x2;

#define AS1 __attribute__((address_space(1)))
#define AS3 __attribute__((address_space(3)))

__device__ __forceinline__ unsigned short f2bf(float x) {
  unsigned int b = __float_as_uint(x);
  return (unsigned short)((b + 0x7FFFu + ((b >> 16) & 1u)) >> 16);
}
__device__ __forceinline__ float bf2f(unsigned short u) {
  return __uint_as_float(((unsigned int)u) << 16);
}
__device__ __forceinline__ float sigm(float x) { return 1.0f / (1.0f + __expf(-x)); }
__device__ __forceinline__ float tanh_fast(float x) { return 1.0f - 2.0f / (__expf(2.0f * x) + 1.0f); }

// ---------------- embedding gather -> bf16
__global__ __launch_bounds__(64) void embed_bf_kernel(const int* __restrict__ dst,
                                                      const float* __restrict__ E,
                                                      unsigned short* __restrict__ embbf) {
  int rt = blockIdx.x;           // t*32 + b
  int t = rt >> 5, b = rt & 31;
  int v = dst[b * T_ + t];
  const float4* src = (const float4*)(E + (size_t)v * D_);
  ushort4* d = (ushort4*)(embbf + (size_t)rt * D_);
  #pragma unroll
  for (int r = 0; r < 2; ++r) {
    float4 x = src[threadIdx.x + r * 64];
    ushort4 o; o.x = f2bf(x.x); o.y = f2bf(x.y); o.z = f2bf(x.z); o.w = f2bf(x.w);
    d[threadIdx.x + r * 64] = o;
  }
}

// ---------------- generic f32 -> bf16
__global__ void cvt_kernel(const float* __restrict__ in, unsigned short* __restrict__ out, int n4) {
  int stride = gridDim.x * blockDim.x;
  for (int i = blockIdx.x * blockDim.x + threadIdx.x; i < n4; i += stride) {
    float4 v = ((const float4*)in)[i];
    ushort4 o; o.x = f2bf(v.x); o.y = f2bf(v.y); o.z = f2bf(v.z); o.w = f2bf(v.w);
    ((ushort4*)out)[i] = o;
  }
}

// ---------------- W1bf[r][c] = bf16(Wih[r][c]), c<512 (row stride 1024)
__global__ void cvt_w1_kernel(const float* __restrict__ Wih, unsigned short* __restrict__ W1bf, int n4) {
  int stride = gridDim.x * blockDim.x;
  for (int i = blockIdx.x * blockDim.x + threadIdx.x; i < n4; i += stride) {
    int flat = i * 4;
    int r = flat >> 9, c = flat & 511;
    float4 v = *(const float4*)(Wih + (size_t)r * 1024 + c);
    ushort4 o; o.x = f2bf(v.x); o.y = f2bf(v.y); o.z = f2bf(v.z); o.w = f2bf(v.w);
    ((ushort4*)W1bf)[i] = o;
  }
}

// ---------------- Wr rows reordered for lane-local epilogue:
// out_row = bid*128 + k_loc*4 + gate  (gate = grow>>9, kg = grow&511)
// per-row 16B-chunk swizzle: chunk ^= (out_row & 7)
__global__ void wr_prep_swz_kernel(const float* __restrict__ Wih, const float* __restrict__ Whh,
                                   unsigned short* __restrict__ Wrs, int n4) {
  int stride = gridDim.x * blockDim.x;
  for (int i = blockIdx.x * blockDim.x + threadIdx.x; i < n4; i += stride) {
    int flat = i * 4;
    int grow = flat >> 9, k = flat & 511;
    float4 a = *(const float4*)(Wih + (size_t)grow * 1024 + 512 + k);
    float4 b = ((const float4*)Whh)[i];
    ushort4 o;
    o.x = f2bf(a.x + b.x); o.y = f2bf(a.y + b.y); o.z = f2bf(a.z + b.z); o.w = f2bf(a.w + b.w);
    int gate = grow >> 9, kgl = grow & 511;
    int orow = (kgl >> 5) * 128 + (kgl & 31) * 4 + gate;
    int chunk = (k >> 3) ^ (orow & 7);
    *(ushort4*)(Wrs + (size_t)orow * 512 + chunk * 8 + (k & 7)) = o;
  }
}

// ---------------- pre-GEMM: preA3[t][kg][b][gate] = bf16(emb . W1 + bias)
__global__ __launch_bounds__(256) void gemm_pre_kernel(
    const unsigned short* __restrict__ A,
    const unsigned short* __restrict__ Bm,
    const float* __restrict__ bih, const float* __restrict__ bhh,
    unsigned short* __restrict__ preA3)
{
  __shared__ unsigned short ldsA[2][128 * 32];
  __shared__ unsigned short ldsB[2][128 * 32];
  const int tid = threadIdx.x;
  const int lane = tid & 63;
  const int wid = tid >> 6;
  const int wm = wid >> 1, wn = wid & 1;
  const int m0 = blockIdx.y * 128;
  const int n0 = blockIdx.x * 128;
  const int srow = lane >> 2;
  const int scol = (lane & 3) * 8;

  f32x4 acc[4][4] = {};
  const int NK = 512 / 32;

  auto stage = [&](int kk, int buf) {
    const int k0 = kk * 32;
    #pragma unroll
    for (int c = 0; c < 2; ++c) {
      const int r = wid * 32 + c * 16;
      const unsigned short* sa = A  + (size_t)(m0 + r + srow) * 512 + k0 + scol;
      const unsigned short* sb = Bm + (size_t)(n0 + r + srow) * 512 + k0 + scol;
      __builtin_amdgcn_global_load_lds((const AS1 void*)sa, (AS3 void*)&ldsA[buf][r * 32], 16, 0, 0);
      __builtin_amdgcn_global_load_lds((const AS1 void*)sb, (AS3 void*)&ldsB[buf][r * 32], 16, 0, 0);
    }
  };

  stage(0, 0);
  __syncthreads();

  const int rl = lane & 15;
  const int kb = lane >> 4;

  for (int kk = 0; kk < NK; ++kk) {
    const int buf = kk & 1;
    if (kk + 1 < NK) stage(kk + 1, buf ^ 1);
    const bf16x8* Af = (const bf16x8*)&ldsA[buf][0];
    const bf16x8* Bf = (const bf16x8*)&ldsB[buf][0];
    bf16x8 av[4], bv[4];
    #pragma unroll
    for (int mi = 0; mi < 4; ++mi) av[mi] = Af[(wm * 64 + mi * 16 + rl) * 4 + kb];
    #pragma unroll
    for (int ni = 0; ni < 4; ++ni) bv[ni] = Bf[(wn * 64 + ni * 16 + rl) * 4 + kb];
    #pragma unroll
    for (int mi = 0; mi < 4; ++mi)
      #pragma unroll
      for (int ni = 0; ni < 4; ++ni)
        acc[mi][ni] = __builtin_amdgcn_mfma_f32_16x16x32_bf16(av[mi], bv[ni], acc[mi][ni], 0, 0, 0);
    __syncthreads();
  }

  const int rb = (lane >> 4) * 4;
  #pragma unroll
  for (int mi = 0; mi < 4; ++mi)
    #pragma unroll
    for (int ni = 0; ni < 4; ++ni) {
      int mbase = m0 + wm * 64 + mi * 16 + rb;
      int col   = n0 + wn * 64 + ni * 16 + rl;
      int gate = col >> 9, kg = col & 511;
      int tt = mbase >> 5, bb0 = mbase & 31;
      float bb = bih[col] + bhh[col];
      #pragma unroll
      for (int j = 0; j < 4; ++j)
        preA3[(((size_t)tt * 512 + kg) * 32 + bb0 + j) * 4 + gate] = f2bf(acc[mi][ni][j] + bb);
    }
}

// ---------------- preA3[t=0][kg][:][gate] += (out0 - h0) @ W2^T  (row r = grow)
__global__ __launch_bounds__(256) void delta0_kernel(const float* __restrict__ Wih,
                                                     const float* __restrict__ out0,
                                                     const float* __restrict__ h0,
                                                     unsigned short* __restrict__ preA3) {
  const int r = blockIdx.x;
  const int tid = threadIdx.x;
  const int b = tid >> 3, seg = tid & 7;
  __shared__ float red[32][9];
  const float4* o4 = (const float4*)(out0 + (size_t)b * 512 + seg * 64);
  const float4* h4 = (const float4*)(h0 + (size_t)b * 512 + seg * 64);
  const float4* w4 = (const float4*)(Wih + (size_t)r * 1024 + 512 + seg * 64);
  float s = 0.f;
  #pragma unroll
  for (int j = 0; j < 16; ++j) {
    float4 o = o4[j], h = h4[j], w = w4[j];
    s += (o.x - h.x) * w.x + (o.y - h.y) * w.y + (o.z - h.z) * w.z + (o.w - h.w) * w.w;
  }
  red[b][seg] = s;
  __syncthreads();
  if (tid < 32) {
    float t = 0.f;
    #pragma unroll
    for (int j = 0; j < 8; ++j) t += red[tid][j];
    int gate = r >> 9, kgl = r & 511;
    unsigned short* p = preA3 + ((size_t)kgl * 32 + tid) * 4 + gate;
    *p = f2bf(bf2f(*p) + t);
  }
}

// ---------------- persistent LSTM, 16 blocks x 1024 threads, TWO PHASES/STEP
// Phase ph handles batches ph*16..ph*16+15 (independent recurrences); while one
// half's published h propagates through the LLC, the block computes the other
// half -> cross-block latency hidden. Lane-local epilogue (W rows reordered so
// MFMA D-fragment gives each lane all 4 gates of one (k,b) cell).
__global__ __launch_bounds__(1024) void lstm_persist_ph_kernel(
    const unsigned short* __restrict__ Wrs,   // [2048][512] reordered+swizzled bf16
    const unsigned short* __restrict__ preA3, // [T][512][32][4] bf16 (bias folded)
    const float* __restrict__ c0,             // [32][512] f32
    unsigned short* __restrict__ hb0,         // [32][512] bf16 ping (h0 at entry)
    unsigned short* __restrict__ hb1,         // pong
    unsigned short* __restrict__ Abf,         // [B*T][512] bf16
    unsigned int* __restrict__ flags)         // 2 x 16 x 64B lines, zeroed each call
{
  __shared__ unsigned short wlds[128 * 512];        // 128 KB, resident
  __shared__ __align__(16) char hexch[16 * 1024];   // 16 KB half-batch h tile
  const int tid = threadIdx.x, bid = blockIdx.x;
  const int lane = tid & 63, wid = tid >> 6;

  // stage 128 reordered W rows once (pre-swizzled source, linear LDS dest)
  #pragma unroll
  for (int it = 0; it < 8; ++it) {
    int r = it * 16 + wid;
    const unsigned short* src = Wrs + ((size_t)bid * 128 + r) * 512 + lane * 8;
    __builtin_amdgcn_global_load_lds((const AS1 void*)src, (AS3 void*)&wlds[r * 512], 16, 0, 0);
  }

  const int half = wid >> 3;                 // waves 0-7: half A, 8-15: half B
  const int rt = wid & 7;
  const int q = lane >> 4, rl = lane & 15;
  const int kg = bid * 32 + rt * 4 + q;      // this lane's k-slot
  const int b = half * 16 + rl;              // this lane's batch
  float c_reg = c0[(size_t)b * 512 + kg];

  const int row = rt * 16 + rl;
  const char* wbase = (const char*)wlds + row * 1024;
  const int rx = (row & 7) << 4;
  const char* hbase = hexch + rl * 1024;
  const int hx = (rl & 7) << 4;

  // stage role: wave srow covers h row srow (1 KB), 16 B per lane
  const int srow = wid;                      // 0..15
  const int sb = lane * 16;
  const int srx = ((srow & 7) << 4);
  char* sbase = hexch + (srow & 15) * 1024;

  __syncthreads();

  for (int t = 0; t < T_; ++t) {
    const unsigned short* hin = (t & 1) ? hb1 : hb0;
    unsigned short* hout = (t & 1) ? hb0 : hb1;
    #pragma unroll
    for (int ph = 0; ph < 2; ++ph) {
      unsigned long long pre = 0;
      if (half == ph)
        pre = *(const unsigned long long*)(preA3 + (((size_t)t * 512 + kg) * 32 + b) * 4);
      if (t > 0) {
        if (tid < 16) {
          unsigned spins = 0;
          while (__hip_atomic_load(&flags[ph * 256 + tid * 16], __ATOMIC_RELAXED,
                                   __HIP_MEMORY_SCOPE_AGENT) < (unsigned)t) {
            if (++spins > 50000000u) break;  // bailout: fail validation, don't hang
          }
        }
      }
      __syncthreads();   // also orders prev phase's hexch reads before stage writes

      // cooperative stage of this half's h (16 KB): 2 agent u64 loads/thread
      {
        const unsigned long long* hs =
            (const unsigned long long*)(hin + (size_t)(ph * 16 + (srow & 15)) * 512) + lane * 2;
        unsigned long long d0 = __hip_atomic_load(hs + 0, __ATOMIC_RELAXED, __HIP_MEMORY_SCOPE_AGENT);
        unsigned long long d1 = __hip_atomic_load(hs + 1, __ATOMIC_RELAXED, __HIP_MEMORY_SCOPE_AGENT);
        u64x2 w; w[0] = d0; w[1] = d1;
        *(u64x2*)(sbase + (sb ^ srx)) = w;
      }
      __syncthreads();

      if (half == ph) {
        f32x4 acc = {}, acc2 = {};
        #pragma unroll
        for (int kk = 0; kk < 16; kk += 2) {
          int k0 = kk * 32 + q * 8;
          int k1 = k0 + 32;
          bf16x8 av0 = *(const bf16x8*)(wbase + ((k0 * 2) ^ rx));
          bf16x8 bv0 = *(const bf16x8*)(hbase + ((k0 * 2) ^ hx));
          bf16x8 av1 = *(const bf16x8*)(wbase + ((k1 * 2) ^ rx));
          bf16x8 bv1 = *(const bf16x8*)(hbase + ((k1 * 2) ^ hx));
          acc  = __builtin_amdgcn_mfma_f32_16x16x32_bf16(av0, bv0, acc, 0, 0, 0);
          acc2 = __builtin_amdgcn_mfma_f32_16x16x32_bf16(av1, bv1, acc2, 0, 0, 0);
        }
        // lane-local epilogue: acc[j] = gate j pre-activation for (kg, b)
        float g0 = acc[0] + acc2[0] + bf2f((unsigned short)(pre));
        float g1 = acc[1] + acc2[1] + bf2f((unsigned short)(pre >> 16));
        float g2 = acc[2] + acc2[2] + bf2f((unsigned short)(pre >> 32));
        float g3 = acc[3] + acc2[3] + bf2f((unsigned short)(pre >> 48));
        float iv = sigm(g0), fv = sigm(g1), gv = tanh_fast(g2), ov = sigm(g3);
        float cn = fv * c_reg + iv * gv;
        c_reg = cn;
        float hn = ov * tanh_fast(cn);
        int hv = (int)f2bf(hn);
        int nb = __shfl(hv, lane + 16);      // partner k-slot (q+1), valid for even q
        if ((q & 1) == 0) {
          unsigned int pair = (unsigned int)hv | ((unsigned int)nb << 16);
          __hip_atomic_store((unsigned int*)(hout + (size_t)b * 512 + kg), pair,
                             __ATOMIC_RELAXED, __HIP_MEMORY_SCOPE_AGENT);
          *(unsigned int*)(Abf + ((size_t)b * T_ + t) * 512 + kg) = pair;
        }
      }
      __syncthreads();   // drain publishes (vmcnt 0 at barrier) before flag

      if (t != T_ - 1 && tid == 0)
        __hip_atomic_store(&flags[ph * 256 + bid * 16], (unsigned)(t + 1),
                           __ATOMIC_RELAXED, __HIP_MEMORY_SCOPE_AGENT);
    }
  }
}

// ---------------- projection GEMM (swizzled LDS, nt C stores) + softmax partials
// grid (32 m-tiles [x, fast], 250 n-tiles [y]) -> consecutive blocks share B panel.
__global__ __launch_bounds__(256) void gemm_kernel(
    const unsigned short* __restrict__ A,
    const unsigned short* __restrict__ Bm,
    float* __restrict__ C,
    float* __restrict__ pmax, float* __restrict__ psum)
{
  __shared__ unsigned short ldsA[2][128 * 32];
  __shared__ unsigned short ldsB[2][128 * 32];
  __shared__ float smax[2][128];
  __shared__ float ssum[2][128];
  const int tid = threadIdx.x;
  const int lane = tid & 63;
  const int wid = tid >> 6;
  const int wm = wid >> 1, wn = wid & 1;
  const int m0 = blockIdx.x * 128;
  const int n0 = blockIdx.y * 128;
  const int srow = lane >> 2;

  f32x4 acc[4][4] = {};
  const int NK = 512 / 32;

  // swizzle: LDS chunk c of row r holds global chunk c ^ ((r>>1)&3)
  auto stage = [&](int kk, int buf) {
    const int k0 = kk * 32;
    const int sw = (srow >> 1) & 3;
    const int gc = ((lane & 3) ^ sw) * 8;
    #pragma unroll
    for (int c = 0; c < 2; ++c) {
      const int r = wid * 32 + c * 16;
      const unsigned short* sa = A  + (size_t)(m0 + r + srow) * 512 + k0 + gc;
      const unsigned short* sb = Bm + (size_t)(n0 + r + srow) * 512 + k0 + gc;
      __builtin_amdgcn_global_load_lds((const AS1 void*)sa, (AS3 void*)&ldsA[buf][r * 32], 16, 0, 0);
      __builtin_amdgcn_global_load_lds((const AS1 void*)sb, (AS3 void*)&ldsB[buf][r * 32], 16, 0, 0);
    }
  };

  stage(0, 0);
  __syncthreads();

  const int rl = lane & 15;
  const int kb = lane >> 4;
  const int rsw = kb ^ ((rl >> 1) & 3);

  for (int kk = 0; kk < NK; ++kk) {
    const int buf = kk & 1;
    if (kk + 1 < NK) stage(kk + 1, buf ^ 1);
    const bf16x8* Af = (const bf16x8*)&ldsA[buf][0];
    const bf16x8* Bf = (const bf16x8*)&ldsB[buf][0];
    bf16x8 av[4], bv[4];
    #pragma unroll
    for (int mi = 0; mi < 4; ++mi) av[mi] = Af[(wm * 64 + mi * 16 + rl) * 4 + rsw];
    #pragma unroll
    for (int ni = 0; ni < 4; ++ni) bv[ni] = Bf[(wn * 64 + ni * 16 + rl) * 4 + rsw];
    #pragma unroll
    for (int mi = 0; mi < 4; ++mi)
      #pragma unroll
      for (int ni = 0; ni < 4; ++ni)
        acc[mi][ni] = __builtin_amdgcn_mfma_f32_16x16x32_bf16(av[mi], bv[ni], acc[mi][ni], 0, 0, 0);
    __syncthreads();
  }

  const int rb = kb * 4;
  #pragma unroll
  for (int mi = 0; mi < 4; ++mi)
    #pragma unroll
    for (int ni = 0; ni < 4; ++ni) {
      size_t rrow = (size_t)(m0 + wm * 64 + mi * 16 + rb);
      size_t col = (size_t)(n0 + wn * 64 + ni * 16 + rl);
      #pragma unroll
      for (int j = 0; j < 4; ++j)
        __builtin_nontemporal_store(acc[mi][ni][j], &C[(rrow + j) * (size_t)V_ + col]);
    }

  // ---- per-tile row max / sum-exp partials ----
  float tm[4][4];
  #pragma unroll
  for (int mi = 0; mi < 4; ++mi)
    #pragma unroll
    for (int j = 0; j < 4; ++j) {
      float m = fmaxf(fmaxf(acc[mi][0][j], acc[mi][1][j]), fmaxf(acc[mi][2][j], acc[mi][3][j]));
      m = fmaxf(m, __shfl_xor(m, 1)); m = fmaxf(m, __shfl_xor(m, 2));
      m = fmaxf(m, __shfl_xor(m, 4)); m = fmaxf(m, __shfl_xor(m, 8));
      tm[mi][j] = m;
    }
  if (rl == 0) {
    #pragma unroll
    for (int mi = 0; mi < 4; ++mi)
      #pragma unroll
      for (int j = 0; j < 4; ++j)
        smax[wn][wm * 64 + mi * 16 + kb * 4 + j] = tm[mi][j];
  }
  __syncthreads();
  float ts[4][4];
  #pragma unroll
  for (int mi = 0; mi < 4; ++mi)
    #pragma unroll
    for (int j = 0; j < 4; ++j) {
      int rlocal = wm * 64 + mi * 16 + kb * 4 + j;
      float M = fmaxf(smax[0][rlocal], smax[1][rlocal]);
      float s = __expf(acc[mi][0][j] - M) + __expf(acc[mi][1][j] - M) +
                __expf(acc[mi][2][j] - M) + __expf(acc[mi][3][j] - M);
      s += __shfl_xor(s, 1); s += __shfl_xor(s, 2);
      s += __shfl_xor(s, 4); s += __shfl_xor(s, 8);
      ts[mi][j] = s;
    }
  if (rl == 0) {
    #pragma unroll
    for (int mi = 0; mi < 4; ++mi)
      #pragma unroll
      for (int j = 0; j < 4; ++j)
        ssum[wn][wm * 64 + mi * 16 + kb * 4 + j] = ts[mi][j];
  }
  __syncthreads();
  if (tid < 128) {
    float M = fmaxf(smax[0][tid], smax[1][tid]);
    float S = ssum[0][tid] + ssum[1][tid];
    pmax[(size_t)(m0 + tid) * 256 + blockIdx.y] = M;
    psum[(size_t)(m0 + tid) * 256 + blockIdx.y] = S;
  }
}

// ---------------- finish: lse from partials, then C[row] -= lse
__global__ __launch_bounds__(256) void softmax_finish_kernel(
    float* __restrict__ C, const float* __restrict__ pmax, const float* __restrict__ psum) {
  const size_t row = blockIdx.x;
  const int tid = threadIdx.x, lane = tid & 63, wid = tid >> 6;
  __shared__ float red[4];

  float pm = (tid < 250) ? pmax[row * 256 + tid] : -INFINITY;
  float ps = (tid < 250) ? psum[row * 256 + tid] : 0.f;

  float m = pm;
  #pragma unroll
  for (int off = 32; off > 0; off >>= 1) m = fmaxf(m, __shfl_xor(m, off));
  if (lane == 0) red[wid] = m;
  __syncthreads();
  m = fmaxf(fmaxf(red[0], red[1]), fmaxf(red[2], red[3]));
  __syncthreads();

  float s = (tid < 250) ? ps * __expf(pm - m) : 0.f;
  #pragma unroll
  for (int off = 32; off > 0; off >>= 1) s += __shfl_xor(s, off);
  if (lane == 0) red[wid] = s;
  __syncthreads();
  s = red[0] + red[1] + red[2] + red[3];
  const float lse = m + logf(s);

  f32x4* p4 = (f32x4*)(C + row * (size_t)V_);
  for (int i = tid; i < 8000; i += 256) {
    f32x4 v = p4[i];
    v -= lse;
    __builtin_nontemporal_store(v, &p4[i]);
  }
}

extern "C" void kernel_launch(void* const* d_in, const int* in_sizes, int n_in,
                              void* d_out, int out_size, void* d_ws, size_t ws_size,
                              hipStream_t stream) {
  const int*   dst  = (const int*)d_in[0];
  const float* E    = (const float*)d_in[1];
  const float* Wih  = (const float*)d_in[2];
  const float* Whh  = (const float*)d_in[3];
  const float* bih  = (const float*)d_in[4];
  const float* bhh  = (const float*)d_in[5];
  const float* h0   = (const float*)d_in[6];
  const float* c0   = (const float*)d_in[7];
  const float* out0 = (const float*)d_in[8];
  float* C = (float*)d_out;

  char* ws = (char*)d_ws;
  unsigned short* Ebf   = (unsigned short*)(ws);                      // 32.77 MB
  unsigned short* preA3 = (unsigned short*)(ws + (size_t)33554432);   // 16.78 MB
  unsigned short* Wrs   = (unsigned short*)(ws + (size_t)50331648);   // 2.10 MB
  unsigned short* embbf = (unsigned short*)(ws + (size_t)52428800);   // pre-phase
  float*          pmax  = (float*)(ws + (size_t)52428800);            // post-phase 4.19 MB
  unsigned short* W1bf  = (unsigned short*)(ws + (size_t)56623104);   // pre-phase
  float*          psum  = (float*)(ws + (size_t)56623104);            // post-phase 4.19 MB
  unsigned short* Abf   = (unsigned short*)(ws + (size_t)60817408);   // 4.19 MB
  unsigned short* hb0   = (unsigned short*)(ws + (size_t)65011712);   // 32 KB
  unsigned short* hb1   = (unsigned short*)(ws + (size_t)65044480);   // 32 KB
  unsigned int*   flg   = (unsigned int*)(ws + (size_t)65077248);     // 2 KB (2 x 16 x 64B)

  (void)hipMemsetAsync(flg, 0, 2048, stream);

  // --- precompute ---
  embed_bf_kernel<<<dim3(T_ * B_), dim3(64), 0, stream>>>(dst, E, embbf);
  cvt_kernel<<<dim3(2048), dim3(256), 0, stream>>>(E, Ebf, V_ * D_ / 4);
  cvt_w1_kernel<<<dim3(256), dim3(256), 0, stream>>>(Wih, W1bf, 2048 * 512 / 4);
  wr_prep_swz_kernel<<<dim3(256), dim3(256), 0, stream>>>(Wih, Whh, Wrs, 2048 * 512 / 4);

  gemm_pre_kernel<<<dim3(2048 / 128, 4096 / 128), dim3(256), 0, stream>>>(embbf, W1bf, bih, bhh, preA3);
  delta0_kernel<<<dim3(2048), dim3(256), 0, stream>>>(Wih, out0, h0, preA3);
  cvt_kernel<<<dim3(16), dim3(256), 0, stream>>>(h0, hb0, B_ * H_ / 4);

  // --- full recurrence, one launch, 16 blocks, phased half-batches ---
  lstm_persist_ph_kernel<<<dim3(16), dim3(1024), 0, stream>>>(Wrs, preA3, c0, hb0, hb1, Abf, flg);

  // --- projection + fused softmax partials ---
  gemm_kernel<<<dim3(32, 250), dim3(256), 0, stream>>>(Abf, Ebf, C, pmax, psum);
  softmax_finish_kernel<<<dim3(B_ * T_), dim3(256), 0, stream>>>(C, pmax, psum);
}